// Round 4
// baseline (326.187 us; speedup 1.0000x reference)
//
#include <hip/hip_runtime.h>
#include <math.h>

// A=32, B=16, C=16, D=16, KK=9, KKA=288, BSZ=4, L=196, BL=784
// po[b_,d] = sum_t G'_d[t,b_] * x[t,b_,d],  G'_d = (H_d + I) @ coeff
//   H_d[t,n] = h_d[(n-t) mod 288] (row-invariant circulant)
//   x = gelu(pu @ mpose_w_d^T + mb_d) via MFMA, same C/D layout as G'.

typedef __attribute__((ext_vector_type(8))) short bf16x8;
typedef __attribute__((ext_vector_type(4))) float f32x4;

__device__ inline float4 ld4(const float* p) { return *reinterpret_cast<const float4*>(p); }
__device__ inline void st4(float* p, float4 v) { *reinterpret_cast<float4*>(p) = v; }
__device__ inline unsigned short f2bf(float f) {
  union { float f; unsigned int i; } v; v.f = f;
  unsigned int r = v.i + 0x7FFFu + ((v.i >> 16) & 1u);
  return (unsigned short)(r >> 16);
}
__device__ inline float gelu_f(float v) {
  return 0.5f * v * (1.f + erff(v * 0.70710678118654752f));
}

// ---------------------------------------------------------------------------
// Kernel 0a: h_d[t] (inverse DFT of the complex filter), doubled, f32.
// ---------------------------------------------------------------------------
__global__ __launch_bounds__(256) void k_htab1(const float* __restrict__ cw,
                                               float* __restrict__ ws_h2) {
  int d = blockIdx.x, tid = threadIdx.x;
  int t = blockIdx.y * 144 + tid;
  if (tid >= 144 || t >= 288) return;
  float acc = cw[(0 * 16 + d) * 2 + 0] +
              ((t & 1) ? -1.f : 1.f) * cw[(144 * 16 + d) * 2 + 0];
  for (int f = 1; f < 144; ++f) {
    int m = (f * t) % 288;
    float th = (float)m * (6.283185307179586f / 288.f);
    float sn, cs;
    sincosf(th, &sn, &cs);
    acc += 2.f * (cw[(f * 16 + d) * 2 + 0] * cs - cw[(f * 16 + d) * 2 + 1] * sn);
  }
  float h = acc * (1.f / 288.f);
  ws_h2[d * 576 + t] = h;
  ws_h2[d * 576 + t + 288] = h;
}

// ---------------------------------------------------------------------------
// Kernel 0b: fragment-ordered (H_d + I) bf16.
// ws_H: [d][mt 18][kk 9][lane 64][j 8]; t = mt*16+(l&15), n = kk*32+(l>>4)*8+j.
// ---------------------------------------------------------------------------
__global__ __launch_bounds__(256) void k_htab2(const float* __restrict__ ws_h2,
                                               unsigned short* __restrict__ ws_H) {
  int d = blockIdx.x, chunk = blockIdx.y, tid = threadIdx.x;
  for (int e = tid; e < 13824; e += 256) {
    int j = e & 7, l = (e >> 3) & 63;
    int kk = (e >> 9) % 9, mtl = (e >> 9) / 9;
    int mt = chunk * 3 + mtl;
    int m = l & 15, g = l >> 4;
    int n = kk * 32 + g * 8 + j, t = mt * 16 + m;
    float v = ws_h2[d * 576 + (n - t + 288)] + ((n == t) ? 1.f : 0.f);
    ws_H[d * 82944 + ((mt * 9 + kk) * 64 + l) * 8 + j] = f2bf(v);
  }
}

// ---------------------------------------------------------------------------
// Kernel 1: per-row prep, thread<->n mapping, pu in registers.
// Writes out_a, ws_pu (compact bf16 A-frags), ws_cb (bf16 coeff B-frags).
// ---------------------------------------------------------------------------
__global__ __launch_bounds__(256) void k_rowprep(
    const float* __restrict__ a_img, const float* __restrict__ pose,
    const float* __restrict__ cpose2_w, const float* __restrict__ cpose2_b,
    const float* __restrict__ ln_g, const float* __restrict__ ln_b,
    const float* __restrict__ sp_w, const float* __restrict__ sp_b,
    float* __restrict__ out_a, unsigned short* __restrict__ ws_pu,
    unsigned short* __restrict__ ws_cb) {
  __shared__ __align__(16) float s_lg[288 * 20];
  __shared__ __align__(16) float s_l2[288 * 20];
  __shared__ __align__(16) float s_au[288];
  __shared__ __align__(16) float s_cw[256];
  __shared__ __align__(16) float s_cb[16];
  __shared__ __align__(16) float s_mu[144], s_rs[144];
  __shared__ float s_sw[81], s_sb[9], s_ga[32], s_be[32];
  __shared__ float s_part[256], s_part2[16];
  __shared__ __align__(16) float s_as[16];
  __shared__ float s_aus;

  int tid = threadIdx.x;
  int row = blockIdx.x;
  int b = row / 196, loc = row % 196, i0 = loc / 14, j0 = loc % 14;

  { int r = tid >> 4, c = tid & 15; s_cw[c * 16 + r] = cpose2_w[r * 16 + c]; }
  if (tid < 16) s_cb[tid] = cpose2_b[tid];
  if (tid < 81) s_sw[tid] = sp_w[tid];
  if (tid < 9)  s_sb[tid] = sp_b[tid];
  if (tid < 32) { s_ga[tid] = ln_g[tid]; s_be[tid] = ln_b[tid]; }
  __syncthreads();

  // Pass1: unfold -> pu regs; ws_pu frags; logit -> s_lg
  for (int n = tid; n < 288; n += 256) {
    int a = n & 31, kk = n >> 5;
    int ki = kk / 3, kj = kk - 3 * ki;
    int yy = i0 + ki - 1, xx = j0 + kj - 1;
    bool ok = (yy >= 0 && yy < 14 && xx >= 0 && xx < 14);
    float pu[16];
#pragma unroll
    for (int c = 0; c < 16; ++c) pu[c] = 0.f;
    float au = 0.f;
    if (ok) {
      const float* pb = pose + ((b * 512 + a * 16) * 14 + yy) * 14 + xx;
#pragma unroll
      for (int c = 0; c < 16; ++c) pu[c] = pb[c * 196];
      au = a_img[((b * 32 + a) * 14 + yy) * 14 + xx];
    }
    s_au[n] = au;
    bf16x8 w0, w1;
#pragma unroll
    for (int j = 0; j < 8; ++j) {
      w0[j] = (short)f2bf(pu[j]);
      w1[j] = (short)f2bf(pu[8 + j]);
    }
    unsigned short* pd = ws_pu + row * 4608 + (n >> 4) * 256 + (n & 15) * 8;
    *reinterpret_cast<bf16x8*>(pd) = w0;
    *reinterpret_cast<bf16x8*>(pd + 128) = w1;
    float acc[16];
#pragma unroll
    for (int q = 0; q < 4; ++q) {
      float4 cb = ld4(&s_cb[4 * q]);
      acc[4 * q + 0] = cb.x; acc[4 * q + 1] = cb.y;
      acc[4 * q + 2] = cb.z; acc[4 * q + 3] = cb.w;
    }
#pragma unroll
    for (int c = 0; c < 16; ++c) {
      float p = pu[c];
#pragma unroll
      for (int q = 0; q < 4; ++q) {
        float4 wv = ld4(&s_cw[c * 16 + 4 * q]);
        acc[4 * q + 0] += p * wv.x; acc[4 * q + 1] += p * wv.y;
        acc[4 * q + 2] += p * wv.z; acc[4 * q + 3] += p * wv.w;
      }
    }
#pragma unroll
    for (int q = 0; q < 4; ++q)
      st4(&s_lg[n * 20 + 4 * q],
          make_float4(acc[4 * q], acc[4 * q + 1], acc[4 * q + 2], acc[4 * q + 3]));
  }
  __syncthreads();

  // Pass2: LayerNorm stats over a per (kk,B)
  if (tid < 144) {
    int kk = tid >> 4, B = tid & 15;
    float s = 0.f, s2 = 0.f;
    for (int a = 0; a < 32; ++a) {
      float v = s_lg[(kk * 32 + a) * 20 + B];
      s += v; s2 += v * v;
    }
    float mu = s * (1.f / 32.f);
    float var = s2 * (1.f / 32.f) - mu * mu;
    s_mu[kk * 16 + B] = mu;
    s_rs[kk * 16 + B] = rsqrtf(var + 1e-5f);
  }
  __syncthreads();

  // Pass3: spatial gate; s_l2 = 2*logit + gelu(conv(LN(logit)))
  for (int n = tid; n < 288; n += 256) {
    int a = n & 31, o = n >> 5;
    float ga = s_ga[a], be = s_be[a];
    float sb = s_sb[o];
    float acc[16];
#pragma unroll
    for (int e = 0; e < 16; ++e) acc[e] = sb;
    for (int i2 = 0; i2 < 9; ++i2) {
      float sw = s_sw[o * 9 + i2];
      const float* lr = &s_lg[(i2 * 32 + a) * 20];
#pragma unroll
      for (int q = 0; q < 4; ++q) {
        float4 v = ld4(lr + 4 * q);
        float4 m = ld4(&s_mu[i2 * 16 + 4 * q]);
        float4 rs = ld4(&s_rs[i2 * 16 + 4 * q]);
        acc[4 * q + 0] += sw * ((v.x - m.x) * rs.x * ga + be);
        acc[4 * q + 1] += sw * ((v.y - m.y) * rs.y * ga + be);
        acc[4 * q + 2] += sw * ((v.z - m.z) * rs.z * ga + be);
        acc[4 * q + 3] += sw * ((v.w - m.w) * rs.w * ga + be);
      }
    }
    const float* lo = &s_lg[n * 20];
#pragma unroll
    for (int q = 0; q < 4; ++q) {
      float4 L = ld4(lo + 4 * q);
      float4 r;
      r.x = 2.f * L.x + gelu_f(acc[4 * q + 0]);
      r.y = 2.f * L.y + gelu_f(acc[4 * q + 1]);
      r.z = 2.f * L.z + gelu_f(acc[4 * q + 2]);
      r.w = 2.f * L.w + gelu_f(acc[4 * q + 3]);
      st4(&s_l2[n * 20 + 4 * q], r);
    }
  }
  __syncthreads();

  // Pass4: softmax over B
  for (int n = tid; n < 288; n += 256) {
    float v[16];
#pragma unroll
    for (int q = 0; q < 4; ++q) {
      float4 t = ld4(&s_l2[n * 20 + 4 * q]);
      v[4 * q] = t.x; v[4 * q + 1] = t.y; v[4 * q + 2] = t.z; v[4 * q + 3] = t.w;
    }
    float m = v[0];
#pragma unroll
    for (int e = 1; e < 16; ++e) m = fmaxf(m, v[e]);
    float s = 0.f;
#pragma unroll
    for (int e = 0; e < 16; ++e) { v[e] = expf(v[e] - m); s += v[e]; }
    float inv = 1.f / s;
#pragma unroll
    for (int q = 0; q < 4; ++q)
      st4(&s_l2[n * 20 + 4 * q],
          make_float4(v[4 * q] * inv, v[4 * q + 1] * inv, v[4 * q + 2] * inv,
                      v[4 * q + 3] * inv));
  }
  __syncthreads();

  // Pass5: ar_sum[B], au_sum (parallel)
  {
    int B = tid & 15, sl = tid >> 4;
    float part = 0.f;
    for (int i = 0; i < 18; ++i) {
      int n = sl * 18 + i;
      part += s_au[n] * s_l2[n * 20 + B];
    }
    s_part[tid] = part;
    if (tid < 16) {
      float pau = 0.f;
      for (int i = 0; i < 18; ++i) pau += s_au[tid * 18 + i];
      s_part2[tid] = pau;
    }
  }
  __syncthreads();
  if (tid < 16) {
    float s = 0.f;
#pragma unroll
    for (int q = 0; q < 16; ++q) s += s_part[tid + 16 * q];
    s_as[tid] = s;
  } else if (tid == 16) {
    float s = 0.f;
#pragma unroll
    for (int q = 0; q < 16; ++q) s += s_part2[q];
    s_aus = s;
  }
  __syncthreads();
  if (tid < 16) out_a[(b * 16 + tid) * 196 + loc] = s_as[tid] / s_aus;

  // Pass6: coeff bf16 B-frags
  for (int e = tid; e < 4608; e += 256) {
    int j = e & 7, B = (e >> 3) & 15, g2 = (e >> 7) & 3, kk = e >> 9;
    int n = kk * 32 + g2 * 8 + j;
    float v = s_au[n] * s_l2[n * 20 + B] / s_as[B];
    ws_cb[row * 4608 + e] = f2bf(v);
  }
}

// ---------------------------------------------------------------------------
// Kernel 2: grid(98, 4): 4 waves/block, wave = 2 rows, inner loop over 4 d.
// coeff B-frags register-resident across the d-loop; H+I streamed from L2.
// ---------------------------------------------------------------------------
__global__ __launch_bounds__(256) void k_gterm(
    const unsigned short* __restrict__ ws_H,
    const unsigned short* __restrict__ ws_pu,
    const unsigned short* __restrict__ ws_cb,
    const float* __restrict__ mpose_w, const float* __restrict__ mpose_b,
    float* __restrict__ out_po) {
  int tid = threadIdx.x;
  int w = tid >> 6, l = tid & 63;
  int p = blockIdx.x * 4 + w;
  int row0 = p * 2, row1 = row0 + 1;
  int d0 = blockIdx.y * 4;
  int b_ = l & 15, g = l >> 4;

  const bf16x8 z8 = {0, 0, 0, 0, 0, 0, 0, 0};
  const f32x4 zf = {0.f, 0.f, 0.f, 0.f};

  // coeff B-frags (persist across d-loop): 2 rows x 9 kk
  bf16x8 c0[9], c1[9];
  {
    const bf16x8* bC0 = (const bf16x8*)ws_cb + row0 * 576;
    const bf16x8* bC1 = (const bf16x8*)ws_cb + row1 * 576;
#pragma unroll
    for (int kk = 0; kk < 9; ++kk) {
      c0[kk] = bC0[kk * 64 + l];
      c1[kk] = bC1[kk * 64 + l];
    }
  }
  const bf16x8* aP0 = (const bf16x8*)ws_pu + row0 * 576;
  const bf16x8* aP1 = (const bf16x8*)ws_pu + row1 * 576;

  int bb = row0 / 196, lc0 = row0 % 196, lc1 = row1 % 196;

  for (int dd = 0; dd < 4; ++dd) {
    int d = d0 + dd;
    bf16x8 bmw = z8;
    if (g < 2) {
      const float* mp = mpose_w + (b_ * 16 + d) * 16 + g * 8;
#pragma unroll
      for (int j = 0; j < 8; ++j) bmw[j] = (short)f2bf(mp[j]);
    }
    float mb = mpose_b[b_ * 16 + d];
    const bf16x8* aH = (const bf16x8*)ws_H + d * 10368;  // 18*9*64

    float po0 = 0.f, po1 = 0.f;
    for (int mt = 0; mt < 18; ++mt) {
      bf16x8 ap0 = z8, ap1 = z8;
      if (g < 2) { ap0 = aP0[mt * 32 + l]; ap1 = aP1[mt * 32 + l]; }
      f32x4 xp0 = __builtin_amdgcn_mfma_f32_16x16x32_bf16(ap0, bmw, zf, 0, 0, 0);
      f32x4 xp1 = __builtin_amdgcn_mfma_f32_16x16x32_bf16(ap1, bmw, zf, 0, 0, 0);
      f32x4 g0 = zf, g1 = zf;
#pragma unroll
      for (int kk = 0; kk < 9; ++kk) {
        bf16x8 a = aH[(mt * 9 + kk) * 64 + l];
        g0 = __builtin_amdgcn_mfma_f32_16x16x32_bf16(a, c0[kk], g0, 0, 0, 0);
        g1 = __builtin_amdgcn_mfma_f32_16x16x32_bf16(a, c1[kk], g1, 0, 0, 0);
      }
#pragma unroll
      for (int r = 0; r < 4; ++r) {
        float s0 = xp0[r] + mb, s1 = xp1[r] + mb;
        po0 += g0[r] * gelu_f(s0);
        po1 += g1[r] * gelu_f(s1);
      }
    }
    po0 += __shfl_xor(po0, 16);
    po0 += __shfl_xor(po0, 32);
    po1 += __shfl_xor(po1, 16);
    po1 += __shfl_xor(po1, 32);
    if (l < 16) {
      out_po[((bb * 256) + l * 16 + d) * 196 + lc0] = po0;
      out_po[((bb * 256) + l * 16 + d) * 196 + lc1] = po1;
    }
  }
}

// ---------------------------------------------------------------------------
extern "C" void kernel_launch(void* const* d_in, const int* in_sizes, int n_in,
                              void* d_out, int out_size, void* d_ws, size_t ws_size,
                              hipStream_t stream) {
  const float* a_img    = (const float*)d_in[0];
  const float* pose     = (const float*)d_in[1];
  const float* mpose_w  = (const float*)d_in[2];
  const float* mpose_b  = (const float*)d_in[3];
  const float* cpose2_w = (const float*)d_in[4];
  const float* cpose2_b = (const float*)d_in[5];
  const float* cw       = (const float*)d_in[6];
  const float* ln_g     = (const float*)d_in[7];
  const float* ln_b     = (const float*)d_in[8];
  const float* sp_w     = (const float*)d_in[9];
  const float* sp_b     = (const float*)d_in[10];

  float* out = (float*)d_out;
  float* ws_h2 = (float*)d_ws;                         // 16*576 f32
  unsigned short* ws_H  = (unsigned short*)(ws_h2 + 16 * 576);  // 16*82944
  unsigned short* ws_pu = ws_H + 16 * 82944;           // 784*4608
  unsigned short* ws_cb = ws_pu + 784 * 4608;          // 784*4608

  hipLaunchKernelGGL(k_htab1, dim3(16, 2), dim3(256), 0, stream, cw, ws_h2);
  hipLaunchKernelGGL(k_htab2, dim3(16, 6), dim3(256), 0, stream, ws_h2, ws_H);
  hipLaunchKernelGGL(k_rowprep, dim3(784), dim3(256), 0, stream,
                     a_img, pose, cpose2_w, cpose2_b, ln_g, ln_b, sp_w, sp_b,
                     out, ws_pu, ws_cb);
  hipLaunchKernelGGL(k_gterm, dim3(98, 4), dim3(256), 0, stream,
                     ws_H, ws_pu, ws_cb, mpose_w, mpose_b, out + 12544);
}

// Round 5
// 226.087 us; speedup vs baseline: 1.4428x; 1.4428x over previous
//
#include <hip/hip_runtime.h>
#include <math.h>

// A=32, B=16, C=16, D=16, KK=9, KKA=288, BSZ=4, L=196, BL=784
// po[b_,d] = sum_t G'_d[t,b_] * x[t,b_,d],  G'_d = (H_d + I) @ coeff
//   H_d[t,n] = h_d[(n-t) mod 288] (row-invariant circulant)
//   x = gelu(pu @ mpose_w_d^T + mb_d) via MFMA, same C/D layout as G'.

typedef __attribute__((ext_vector_type(8))) short bf16x8;
typedef __attribute__((ext_vector_type(4))) float f32x4;

__device__ inline unsigned short f2bf(float f) {
  union { float f; unsigned int i; } v; v.f = f;
  unsigned int r = v.i + 0x7FFFu + ((v.i >> 16) & 1u);
  return (unsigned short)(r >> 16);
}
__device__ inline float gelu_f(float v) {
  return 0.5f * v * (1.f + erff(v * 0.70710678118654752f));
}

// ---------------------------------------------------------------------------
// Kernel 0a: h_d[t] (inverse DFT of the complex filter), doubled, f32.
// ---------------------------------------------------------------------------
__global__ __launch_bounds__(256) void k_htab1(const float* __restrict__ cw,
                                               float* __restrict__ ws_h2) {
  int d = blockIdx.x, tid = threadIdx.x;
  int t = blockIdx.y * 144 + tid;
  if (tid >= 144 || t >= 288) return;
  float acc = cw[(0 * 16 + d) * 2 + 0] +
              ((t & 1) ? -1.f : 1.f) * cw[(144 * 16 + d) * 2 + 0];
  for (int f = 1; f < 144; ++f) {
    int m = (f * t) % 288;
    float th = (float)m * (6.283185307179586f / 288.f);
    float sn, cs;
    sincosf(th, &sn, &cs);
    acc += 2.f * (cw[(f * 16 + d) * 2 + 0] * cs - cw[(f * 16 + d) * 2 + 1] * sn);
  }
  float h = acc * (1.f / 288.f);
  ws_h2[d * 576 + t] = h;
  ws_h2[d * 576 + t + 288] = h;
}

// ---------------------------------------------------------------------------
// Kernel 0b: fragment-ordered (H_d + I) bf16.
// ws_H: [d][mt 18][kk 9][lane 64][j 8]; t = mt*16+(l&15), n = kk*32+(l>>4)*8+j.
// ---------------------------------------------------------------------------
__global__ __launch_bounds__(256) void k_htab2(const float* __restrict__ ws_h2,
                                               unsigned short* __restrict__ ws_H) {
  int d = blockIdx.x, chunk = blockIdx.y, tid = threadIdx.x;
  for (int e = tid; e < 13824; e += 256) {
    int j = e & 7, l = (e >> 3) & 63;
    int kk = (e >> 9) % 9, mtl = (e >> 9) / 9;
    int mt = chunk * 3 + mtl;
    int m = l & 15, g = l >> 4;
    int n = kk * 32 + g * 8 + j, t = mt * 16 + m;
    float v = ws_h2[d * 576 + (n - t + 288)] + ((n == t) ? 1.f : 0.f);
    ws_H[d * 82944 + ((mt * 9 + kk) * 64 + l) * 8 + j] = f2bf(v);
  }
}

// ---------------------------------------------------------------------------
// Kernel 1: per-row prep (round-1 structure — measured ~20us), frag-format
// outputs: ws_pu compact bf16 A-frags, ws_cb bf16 coeff B-frags.
// ---------------------------------------------------------------------------
__global__ __launch_bounds__(256) void k_rowprep(
    const float* __restrict__ a_img, const float* __restrict__ pose,
    const float* __restrict__ cpose2_w, const float* __restrict__ cpose2_b,
    const float* __restrict__ ln_g, const float* __restrict__ ln_b,
    const float* __restrict__ sp_w, const float* __restrict__ sp_b,
    float* __restrict__ out_a, unsigned short* __restrict__ ws_pu,
    unsigned short* __restrict__ ws_cb) {
  __shared__ float s_pu[288 * 17];
  __shared__ float s_lg[288 * 17];
  __shared__ float s_l2[288 * 17];
  __shared__ float s_au[288];
  __shared__ float s_mu[16 * 9], s_rs[16 * 9];
  __shared__ float s_cw[256];
  __shared__ float s_cb[16], s_sw[81], s_sb[9], s_ga[32], s_be[32];
  __shared__ float s_as[16];
  __shared__ float s_aus;

  int tid = threadIdx.x;
  int row = blockIdx.x;
  int b = row / 196, l = row % 196, i0 = l / 14, j0 = l % 14;

  { int r = tid >> 4, c = tid & 15; s_cw[c * 16 + r] = cpose2_w[r * 16 + c]; }
  if (tid < 16) s_cb[tid] = cpose2_b[tid];
  if (tid < 81) s_sw[tid] = sp_w[tid];
  if (tid < 9)  s_sb[tid] = sp_b[tid];
  if (tid < 32) { s_ga[tid] = ln_g[tid]; s_be[tid] = ln_b[tid]; }

  for (int idx = tid; idx < 4608; idx += 256) {
    int n = idx >> 4, c = idx & 15;
    int a = n & 31, kk = n >> 5;
    int ki = kk / 3, kj = kk - 3 * ki;
    int yy = i0 + ki - 1, xx = j0 + kj - 1;
    float v = 0.f;
    if (yy >= 0 && yy < 14 && xx >= 0 && xx < 14)
      v = pose[((b * 512 + a * 16 + c) * 14 + yy) * 14 + xx];
    s_pu[n * 17 + c] = v;
  }
  for (int n = tid; n < 288; n += 256) {
    int a = n & 31, kk = n >> 5;
    int ki = kk / 3, kj = kk - 3 * ki;
    int yy = i0 + ki - 1, xx = j0 + kj - 1;
    float v = 0.f;
    if (yy >= 0 && yy < 14 && xx >= 0 && xx < 14)
      v = a_img[((b * 32 + a) * 14 + yy) * 14 + xx];
    s_au[n] = v;
  }
  __syncthreads();

  for (int idx = tid; idx < 4608; idx += 256) {
    int n = idx >> 4, B = idx & 15;
    float acc = s_cb[B];
#pragma unroll
    for (int c = 0; c < 16; ++c) acc += s_pu[n * 17 + c] * s_cw[c * 16 + B];
    s_lg[n * 17 + B] = acc;
  }
  __syncthreads();

  if (tid < 144) {
    int kk = tid >> 4, B = tid & 15;
    float s = 0.f, s2 = 0.f;
    for (int a = 0; a < 32; ++a) {
      float v = s_lg[(kk * 32 + a) * 17 + B];
      s += v; s2 += v * v;
    }
    float mu = s * (1.f / 32.f);
    float var = s2 * (1.f / 32.f) - mu * mu;
    s_mu[B * 9 + kk] = mu;
    s_rs[B * 9 + kk] = rsqrtf(var + 1e-5f);
  }
  __syncthreads();

  for (int idx = tid; idx < 4608; idx += 256) {
    int n = idx >> 4, B = idx & 15;
    int o = n >> 5, a = n & 31;
    float acc = s_sb[o];
#pragma unroll
    for (int i2 = 0; i2 < 9; ++i2) {
      float v = s_lg[(i2 * 32 + a) * 17 + B];
      float gn = (v - s_mu[B * 9 + i2]) * s_rs[B * 9 + i2] * s_ga[a] + s_be[a];
      acc += s_sw[o * 9 + i2] * gn;
    }
    float ge = 0.5f * acc * (1.f + erff(acc * 0.70710678118654752f));
    s_l2[n * 17 + B] = 2.f * s_lg[n * 17 + B] + ge;
  }
  __syncthreads();

  for (int n = tid; n < 288; n += 256) {
    float m = -1e30f;
#pragma unroll
    for (int B = 0; B < 16; ++B) m = fmaxf(m, s_l2[n * 17 + B]);
    float sum = 0.f;
#pragma unroll
    for (int B = 0; B < 16; ++B) {
      float e = expf(s_l2[n * 17 + B] - m);
      s_l2[n * 17 + B] = e;
      sum += e;
    }
    float inv = 1.f / sum;
#pragma unroll
    for (int B = 0; B < 16; ++B) s_l2[n * 17 + B] *= inv;
  }
  __syncthreads();

  if (tid < 16) {
    float s = 0.f;
    for (int n = 0; n < 288; ++n) s += s_au[n] * s_l2[n * 17 + tid];
    s_as[tid] = s;
  } else if (tid == 16) {
    float s = 0.f;
    for (int n = 0; n < 288; ++n) s += s_au[n];
    s_aus = s;
  }
  __syncthreads();

  if (tid < 16) out_a[(b * 16 + tid) * 196 + l] = s_as[tid] / s_aus;

  // coeff B-frags bf16: e = ((kk*4+g)*16 + b_)*8 + j, n = kk*32+g*8+j
  for (int e = tid; e < 4608; e += 256) {
    int j = e & 7, B = (e >> 3) & 15, g2 = (e >> 7) & 3, kk = e >> 9;
    int n = kk * 32 + g2 * 8 + j;
    float v = s_au[n] * s_l2[n * 17 + B] / s_as[B];
    ws_cb[row * 4608 + e] = f2bf(v);
  }
  // pu compact A-frags: e = (mt*32 + l2)*8 + j, t = mt*16+(l2&15), c=(l2>>4)*8+j
  for (int e = tid; e < 4608; e += 256) {
    int j = e & 7, l2 = (e >> 3) & 31, mt = e >> 8;
    int m = l2 & 15, c = (l2 >> 4) * 8 + j;
    ws_pu[row * 4608 + e] = f2bf(s_pu[(mt * 16 + m) * 17 + c]);
  }
}

// ---------------------------------------------------------------------------
// Kernel 2: grid(49, 16): 8 waves/block, wave = 2 rows, d = blockIdx.y.
// H_d mt-tiles (9KB) double-buffered in LDS; coeff frags VGPR-resident.
// ---------------------------------------------------------------------------
__global__ __launch_bounds__(512, 2) void k_gterm(
    const unsigned short* __restrict__ ws_H,
    const unsigned short* __restrict__ ws_pu,
    const unsigned short* __restrict__ ws_cb,
    const float* __restrict__ mpose_w, const float* __restrict__ mpose_b,
    float* __restrict__ out_po) {
  __shared__ uint4 s_H4[2][576];   // 2 x 9KB (9 kk x 64 lanes x 16B)

  int tid = threadIdx.x;
  int w = tid >> 6, l = tid & 63;
  int rg = blockIdx.x, d = blockIdx.y;
  int row0 = rg * 16 + w * 2, row1 = row0 + 1;
  int b_ = l & 15, g = l >> 4;

  const bf16x8 z8 = {0, 0, 0, 0, 0, 0, 0, 0};
  const f32x4 zf = {0.f, 0.f, 0.f, 0.f};

  // mpose_w B-frag (k = c, zero-padded c>=16) + bias
  bf16x8 bmw = z8;
  if (g < 2) {
    const float* mp = mpose_w + (b_ * 16 + d) * 16 + g * 8;
#pragma unroll
    for (int j = 0; j < 8; ++j) bmw[j] = (short)f2bf(mp[j]);
  }
  float mb = mpose_b[b_ * 16 + d];

  // coeff B-frags, VGPR-resident for the whole kernel (d fixed per block)
  bf16x8 c0[9], c1[9];
  {
    const bf16x8* bC0 = (const bf16x8*)ws_cb + row0 * 576;
    const bf16x8* bC1 = (const bf16x8*)ws_cb + row1 * 576;
#pragma unroll
    for (int kk = 0; kk < 9; ++kk) {
      c0[kk] = bC0[kk * 64 + l];
      c1[kk] = bC1[kk * 64 + l];
    }
  }
  const bf16x8* aP0 = (const bf16x8*)ws_pu + row0 * 576;
  const bf16x8* aP1 = (const bf16x8*)ws_pu + row1 * 576;
  const uint4* gH = (const uint4*)(ws_H + d * 82944);  // [mt*9+kk]*64+l

  // prologue: stage tile 0
  {
    uint4 p0 = gH[w * 64 + l];
    uint4 p1 = {0, 0, 0, 0};
    if (w == 0) p1 = gH[8 * 64 + l];
    s_H4[0][w * 64 + l] = p0;
    if (w == 0) s_H4[0][8 * 64 + l] = p1;
  }
  __syncthreads();

  float po0 = 0.f, po1 = 0.f;
  for (int mt = 0; mt < 18; ++mt) {
    int cur = mt & 1;
    // issue next-tile global loads (latency hides under compute)
    uint4 n0 = {0, 0, 0, 0}, n1 = {0, 0, 0, 0};
    if (mt < 17) {
      n0 = gH[((mt + 1) * 9 + w) * 64 + l];
      if (w == 0) n1 = gH[((mt + 1) * 9 + 8) * 64 + l];
    }
    // x pre-activation tiles (same C/D layout as G)
    bf16x8 ap0 = z8, ap1 = z8;
    if (g < 2) { ap0 = aP0[mt * 32 + l]; ap1 = aP1[mt * 32 + l]; }
    f32x4 xp0 = __builtin_amdgcn_mfma_f32_16x16x32_bf16(ap0, bmw, zf, 0, 0, 0);
    f32x4 xp1 = __builtin_amdgcn_mfma_f32_16x16x32_bf16(ap1, bmw, zf, 0, 0, 0);
    // G' tiles from LDS
    f32x4 g0 = zf, g1 = zf;
#pragma unroll
    for (int kk = 0; kk < 9; ++kk) {
      bf16x8 h = *(const bf16x8*)&s_H4[cur][kk * 64 + l];
      g0 = __builtin_amdgcn_mfma_f32_16x16x32_bf16(h, c0[kk], g0, 0, 0, 0);
      g1 = __builtin_amdgcn_mfma_f32_16x16x32_bf16(h, c1[kk], g1, 0, 0, 0);
    }
    // epilogue: po += G' * gelu(xpre + mb)
#pragma unroll
    for (int r = 0; r < 4; ++r) {
      float s0 = xp0[r] + mb, s1 = xp1[r] + mb;
      po0 += g0[r] * gelu_f(s0);
      po1 += g1[r] * gelu_f(s1);
    }
    // write next tile, one barrier per mt
    if (mt < 17) {
      s_H4[cur ^ 1][w * 64 + l] = n0;
      if (w == 0) s_H4[cur ^ 1][8 * 64 + l] = n1;
      __syncthreads();
    }
  }

  po0 += __shfl_xor(po0, 16);
  po0 += __shfl_xor(po0, 32);
  po1 += __shfl_xor(po1, 16);
  po1 += __shfl_xor(po1, 32);
  if (l < 16) {
    int bb = row0 / 196, lc0 = row0 % 196, lc1 = row1 % 196;
    out_po[((bb * 256) + l * 16 + d) * 196 + lc0] = po0;
    out_po[((bb * 256) + l * 16 + d) * 196 + lc1] = po1;
  }
}

// ---------------------------------------------------------------------------
extern "C" void kernel_launch(void* const* d_in, const int* in_sizes, int n_in,
                              void* d_out, int out_size, void* d_ws, size_t ws_size,
                              hipStream_t stream) {
  const float* a_img    = (const float*)d_in[0];
  const float* pose     = (const float*)d_in[1];
  const float* mpose_w  = (const float*)d_in[2];
  const float* mpose_b  = (const float*)d_in[3];
  const float* cpose2_w = (const float*)d_in[4];
  const float* cpose2_b = (const float*)d_in[5];
  const float* cw       = (const float*)d_in[6];
  const float* ln_g     = (const float*)d_in[7];
  const float* ln_b     = (const float*)d_in[8];
  const float* sp_w     = (const float*)d_in[9];
  const float* sp_b     = (const float*)d_in[10];

  float* out = (float*)d_out;
  float* ws_h2 = (float*)d_ws;                                  // 16*576 f32
  unsigned short* ws_H  = (unsigned short*)(ws_h2 + 16 * 576);  // 16*82944
  unsigned short* ws_pu = ws_H + 16 * 82944;                    // 784*4608
  unsigned short* ws_cb = ws_pu + 784 * 4608;                   // 784*4608

  hipLaunchKernelGGL(k_htab1, dim3(16, 2), dim3(256), 0, stream, cw, ws_h2);
  hipLaunchKernelGGL(k_htab2, dim3(16, 6), dim3(256), 0, stream, ws_h2, ws_H);
  hipLaunchKernelGGL(k_rowprep, dim3(784), dim3(256), 0, stream,
                     a_img, pose, cpose2_w, cpose2_b, ln_g, ln_b, sp_w, sp_b,
                     out, ws_pu, ws_cb);
  hipLaunchKernelGGL(k_gterm, dim3(49, 16), dim3(512), 0, stream,
                     ws_H, ws_pu, ws_cb, mpose_w, mpose_b, out + 12544);
}

// Round 6
// 215.978 us; speedup vs baseline: 1.5103x; 1.0468x over previous
//
#include <hip/hip_runtime.h>
#include <math.h>

// A=32, B=16, C=16, D=16, KK=9, KKA=288, BSZ=4, L=196, BL=784
// po[b_,d] = sum_t G'_d[t,b_] * x[t,b_,d],  G'_d = (H_d + I) @ coeff
//   H_d[t,n] = h_d[(n-t) mod 288] (row-invariant circulant)
//   x = gelu(pu @ mpose_w_d^T + mb_d) via MFMA, same C/D layout as G'.

typedef __attribute__((ext_vector_type(8))) short bf16x8;
typedef __attribute__((ext_vector_type(4))) float f32x4;

__device__ inline unsigned short f2bf(float f) {
  union { float f; unsigned int i; } v; v.f = f;
  unsigned int r = v.i + 0x7FFFu + ((v.i >> 16) & 1u);
  return (unsigned short)(r >> 16);
}
__device__ inline float gelu_f(float v) {
  return 0.5f * v * (1.f + erff(v * 0.70710678118654752f));
}

// ---------------------------------------------------------------------------
// Kernel 0a: h_d[t] (inverse DFT of the complex filter), doubled, f32.
// ---------------------------------------------------------------------------
__global__ __launch_bounds__(256) void k_htab1(const float* __restrict__ cw,
                                               float* __restrict__ ws_h2) {
  int d = blockIdx.x, tid = threadIdx.x;
  int t = blockIdx.y * 144 + tid;
  if (tid >= 144 || t >= 288) return;
  float acc = cw[(0 * 16 + d) * 2 + 0] +
              ((t & 1) ? -1.f : 1.f) * cw[(144 * 16 + d) * 2 + 0];
  for (int f = 1; f < 144; ++f) {
    int m = (f * t) % 288;
    float th = (float)m * (6.283185307179586f / 288.f);
    float sn, cs;
    sincosf(th, &sn, &cs);
    acc += 2.f * (cw[(f * 16 + d) * 2 + 0] * cs - cw[(f * 16 + d) * 2 + 1] * sn);
  }
  float h = acc * (1.f / 288.f);
  ws_h2[d * 576 + t] = h;
  ws_h2[d * 576 + t + 288] = h;
}

// ---------------------------------------------------------------------------
// Kernel 0b: fragment-ordered (H_d + I) bf16.
// ws_H: [d][mt 18][kk 9][lane 64][j 8]; t = mt*16+(l&15), n = kk*32+(l>>4)*8+j.
// ---------------------------------------------------------------------------
__global__ __launch_bounds__(256) void k_htab2(const float* __restrict__ ws_h2,
                                               unsigned short* __restrict__ ws_H) {
  int d = blockIdx.x, chunk = blockIdx.y, tid = threadIdx.x;
  for (int e = tid; e < 13824; e += 256) {
    int j = e & 7, l = (e >> 3) & 63;
    int kk = (e >> 9) % 9, mtl = (e >> 9) / 9;
    int mt = chunk * 3 + mtl;
    int m = l & 15, g = l >> 4;
    int n = kk * 32 + g * 8 + j, t = mt * 16 + m;
    float v = ws_h2[d * 576 + (n - t + 288)] + ((n == t) ? 1.f : 0.f);
    ws_H[d * 82944 + ((mt * 9 + kk) * 64 + l) * 8 + j] = f2bf(v);
  }
}

// ---------------------------------------------------------------------------
// Kernel 1: per-row prep (round-1 structure), frag-format outputs.
// ---------------------------------------------------------------------------
__global__ __launch_bounds__(256) void k_rowprep(
    const float* __restrict__ a_img, const float* __restrict__ pose,
    const float* __restrict__ cpose2_w, const float* __restrict__ cpose2_b,
    const float* __restrict__ ln_g, const float* __restrict__ ln_b,
    const float* __restrict__ sp_w, const float* __restrict__ sp_b,
    float* __restrict__ out_a, unsigned short* __restrict__ ws_pu,
    unsigned short* __restrict__ ws_cb) {
  __shared__ float s_pu[288 * 17];
  __shared__ float s_lg[288 * 17];
  __shared__ float s_l2[288 * 17];
  __shared__ float s_au[288];
  __shared__ float s_mu[16 * 9], s_rs[16 * 9];
  __shared__ float s_cw[256];
  __shared__ float s_cb[16], s_sw[81], s_sb[9], s_ga[32], s_be[32];
  __shared__ float s_as[16];
  __shared__ float s_aus;

  int tid = threadIdx.x;
  int row = blockIdx.x;
  int b = row / 196, l = row % 196, i0 = l / 14, j0 = l % 14;

  { int r = tid >> 4, c = tid & 15; s_cw[c * 16 + r] = cpose2_w[r * 16 + c]; }
  if (tid < 16) s_cb[tid] = cpose2_b[tid];
  if (tid < 81) s_sw[tid] = sp_w[tid];
  if (tid < 9)  s_sb[tid] = sp_b[tid];
  if (tid < 32) { s_ga[tid] = ln_g[tid]; s_be[tid] = ln_b[tid]; }

  for (int idx = tid; idx < 4608; idx += 256) {
    int n = idx >> 4, c = idx & 15;
    int a = n & 31, kk = n >> 5;
    int ki = kk / 3, kj = kk - 3 * ki;
    int yy = i0 + ki - 1, xx = j0 + kj - 1;
    float v = 0.f;
    if (yy >= 0 && yy < 14 && xx >= 0 && xx < 14)
      v = pose[((b * 512 + a * 16 + c) * 14 + yy) * 14 + xx];
    s_pu[n * 17 + c] = v;
  }
  for (int n = tid; n < 288; n += 256) {
    int a = n & 31, kk = n >> 5;
    int ki = kk / 3, kj = kk - 3 * ki;
    int yy = i0 + ki - 1, xx = j0 + kj - 1;
    float v = 0.f;
    if (yy >= 0 && yy < 14 && xx >= 0 && xx < 14)
      v = a_img[((b * 32 + a) * 14 + yy) * 14 + xx];
    s_au[n] = v;
  }
  __syncthreads();

  for (int idx = tid; idx < 4608; idx += 256) {
    int n = idx >> 4, B = idx & 15;
    float acc = s_cb[B];
#pragma unroll
    for (int c = 0; c < 16; ++c) acc += s_pu[n * 17 + c] * s_cw[c * 16 + B];
    s_lg[n * 17 + B] = acc;
  }
  __syncthreads();

  if (tid < 144) {
    int kk = tid >> 4, B = tid & 15;
    float s = 0.f, s2 = 0.f;
    for (int a = 0; a < 32; ++a) {
      float v = s_lg[(kk * 32 + a) * 17 + B];
      s += v; s2 += v * v;
    }
    float mu = s * (1.f / 32.f);
    float var = s2 * (1.f / 32.f) - mu * mu;
    s_mu[B * 9 + kk] = mu;
    s_rs[B * 9 + kk] = rsqrtf(var + 1e-5f);
  }
  __syncthreads();

  for (int idx = tid; idx < 4608; idx += 256) {
    int n = idx >> 4, B = idx & 15;
    int o = n >> 5, a = n & 31;
    float acc = s_sb[o];
#pragma unroll
    for (int i2 = 0; i2 < 9; ++i2) {
      float v = s_lg[(i2 * 32 + a) * 17 + B];
      float gn = (v - s_mu[B * 9 + i2]) * s_rs[B * 9 + i2] * s_ga[a] + s_be[a];
      acc += s_sw[o * 9 + i2] * gn;
    }
    float ge = 0.5f * acc * (1.f + erff(acc * 0.70710678118654752f));
    s_l2[n * 17 + B] = 2.f * s_lg[n * 17 + B] + ge;
  }
  __syncthreads();

  for (int n = tid; n < 288; n += 256) {
    float m = -1e30f;
#pragma unroll
    for (int B = 0; B < 16; ++B) m = fmaxf(m, s_l2[n * 17 + B]);
    float sum = 0.f;
#pragma unroll
    for (int B = 0; B < 16; ++B) {
      float e = expf(s_l2[n * 17 + B] - m);
      s_l2[n * 17 + B] = e;
      sum += e;
    }
    float inv = 1.f / sum;
#pragma unroll
    for (int B = 0; B < 16; ++B) s_l2[n * 17 + B] *= inv;
  }
  __syncthreads();

  if (tid < 16) {
    float s = 0.f;
    for (int n = 0; n < 288; ++n) s += s_au[n] * s_l2[n * 17 + tid];
    s_as[tid] = s;
  } else if (tid == 16) {
    float s = 0.f;
    for (int n = 0; n < 288; ++n) s += s_au[n];
    s_aus = s;
  }
  __syncthreads();

  if (tid < 16) out_a[(b * 16 + tid) * 196 + l] = s_as[tid] / s_aus;

  // coeff B-frags bf16: e = ((kk*4+g)*16 + b_)*8 + j, n = kk*32+g*8+j
  for (int e = tid; e < 4608; e += 256) {
    int j = e & 7, B = (e >> 3) & 15, g2 = (e >> 7) & 3, kk = e >> 9;
    int n = kk * 32 + g2 * 8 + j;
    float v = s_au[n] * s_l2[n * 17 + B] / s_as[B];
    ws_cb[row * 4608 + e] = f2bf(v);
  }
  // pu compact A-frags: e = (mt*32 + l2)*8 + j, t = mt*16+(l2&15), c=(l2>>4)*8+j
  for (int e = tid; e < 4608; e += 256) {
    int j = e & 7, l2 = (e >> 3) & 31, mt = e >> 8;
    int m = l2 & 15, c = (l2 >> 4) * 8 + j;
    ws_pu[row * 4608 + e] = f2bf(s_pu[(mt * 16 + m) * 17 + c]);
  }
}

// ---------------------------------------------------------------------------
// Kernel 2: 1-D grid 896 with XCD-affinity decode (rg%8 == bid%8).
// 8 waves/block, wave = 2 rows. H_d mt-tiles double-buffered in LDS.
// Coeff frags pinned in VGPRs via asm (prevents rematerialization).
// ---------------------------------------------------------------------------
__global__ __launch_bounds__(512, 2) void k_gterm(
    const unsigned short* __restrict__ ws_H,
    const unsigned short* __restrict__ ws_pu,
    const unsigned short* __restrict__ ws_cb,
    const float* __restrict__ mpose_w, const float* __restrict__ mpose_b,
    float* __restrict__ out_po) {
  __shared__ uint4 s_H4[2][576];   // 2 x 9KB (9 kk x 64 lanes x 16B)

  int bid = blockIdx.x;
  int xcd = bid & 7, q = bid >> 3;
  int rg = xcd + 8 * (q % 7);
  int d = q / 7;
  if (rg >= 49) return;

  int tid = threadIdx.x;
  int w = tid >> 6, l = tid & 63;
  int row0 = rg * 16 + w * 2, row1 = row0 + 1;
  int b_ = l & 15, g = l >> 4;

  const bf16x8 z8 = {0, 0, 0, 0, 0, 0, 0, 0};
  const f32x4 zf = {0.f, 0.f, 0.f, 0.f};

  // mpose_w B-frag (k = c, zero-padded c>=16) + bias
  bf16x8 bmw = z8;
  if (g < 2) {
    const float* mp = mpose_w + (b_ * 16 + d) * 16 + g * 8;
#pragma unroll
    for (int j = 0; j < 8; ++j) bmw[j] = (short)f2bf(mp[j]);
  }
  float mb = mpose_b[b_ * 16 + d];

  // coeff B-frags, pinned VGPR-resident (asm blocks rematerialization)
  union CU { uint4 u; bf16x8 v; };
  CU c0[9], c1[9];
  {
    const uint4* gC0 = (const uint4*)ws_cb + row0 * 576;
    const uint4* gC1 = (const uint4*)ws_cb + row1 * 576;
#pragma unroll
    for (int kk = 0; kk < 9; ++kk) {
      c0[kk].u = gC0[kk * 64 + l];
      c1[kk].u = gC1[kk * 64 + l];
    }
#pragma unroll
    for (int kk = 0; kk < 9; ++kk) {
      asm volatile("" : "+v"(c0[kk].u.x), "+v"(c0[kk].u.y),
                        "+v"(c0[kk].u.z), "+v"(c0[kk].u.w));
      asm volatile("" : "+v"(c1[kk].u.x), "+v"(c1[kk].u.y),
                        "+v"(c1[kk].u.z), "+v"(c1[kk].u.w));
    }
  }
  const bf16x8* aP0 = (const bf16x8*)ws_pu + row0 * 576;
  const bf16x8* aP1 = (const bf16x8*)ws_pu + row1 * 576;
  const uint4* gH = (const uint4*)(ws_H + d * 82944);  // [mt*9+kk]*64+l

  // prologue: stage tile 0
  {
    uint4 p0 = gH[w * 64 + l];
    uint4 p1 = {0, 0, 0, 0};
    if (w == 0) p1 = gH[8 * 64 + l];
    s_H4[0][w * 64 + l] = p0;
    if (w == 0) s_H4[0][8 * 64 + l] = p1;
  }
  __syncthreads();

  float po0 = 0.f, po1 = 0.f;
  for (int mt = 0; mt < 18; ++mt) {
    int cur = mt & 1;
    // issue next-tile global loads (latency hides under compute)
    uint4 n0 = {0, 0, 0, 0}, n1 = {0, 0, 0, 0};
    if (mt < 17) {
      n0 = gH[((mt + 1) * 9 + w) * 64 + l];
      if (w == 0) n1 = gH[((mt + 1) * 9 + 8) * 64 + l];
    }
    // x pre-activation tiles (same C/D layout as G)
    bf16x8 ap0 = z8, ap1 = z8;
    if (g < 2) { ap0 = aP0[mt * 32 + l]; ap1 = aP1[mt * 32 + l]; }
    f32x4 xp0 = __builtin_amdgcn_mfma_f32_16x16x32_bf16(ap0, bmw, zf, 0, 0, 0);
    f32x4 xp1 = __builtin_amdgcn_mfma_f32_16x16x32_bf16(ap1, bmw, zf, 0, 0, 0);
    // G' tiles from LDS
    f32x4 g0 = zf, g1 = zf;
#pragma unroll
    for (int kk = 0; kk < 9; ++kk) {
      bf16x8 h = *(const bf16x8*)&s_H4[cur][kk * 64 + l];
      g0 = __builtin_amdgcn_mfma_f32_16x16x32_bf16(h, c0[kk].v, g0, 0, 0, 0);
      g1 = __builtin_amdgcn_mfma_f32_16x16x32_bf16(h, c1[kk].v, g1, 0, 0, 0);
    }
    // epilogue: po += G' * gelu(xpre + mb)
#pragma unroll
    for (int r = 0; r < 4; ++r) {
      float s0 = xp0[r] + mb, s1 = xp1[r] + mb;
      po0 += g0[r] * gelu_f(s0);
      po1 += g1[r] * gelu_f(s1);
    }
    // write next tile, one barrier per mt
    if (mt < 17) {
      s_H4[cur ^ 1][w * 64 + l] = n0;
      if (w == 0) s_H4[cur ^ 1][8 * 64 + l] = n1;
      __syncthreads();
    }
  }

  po0 += __shfl_xor(po0, 16);
  po0 += __shfl_xor(po0, 32);
  po1 += __shfl_xor(po1, 16);
  po1 += __shfl_xor(po1, 32);
  if (l < 16) {
    int bb = row0 / 196, lc0 = row0 % 196, lc1 = row1 % 196;
    out_po[((bb * 256) + l * 16 + d) * 196 + lc0] = po0;
    out_po[((bb * 256) + l * 16 + d) * 196 + lc1] = po1;
  }
}

// ---------------------------------------------------------------------------
extern "C" void kernel_launch(void* const* d_in, const int* in_sizes, int n_in,
                              void* d_out, int out_size, void* d_ws, size_t ws_size,
                              hipStream_t stream) {
  const float* a_img    = (const float*)d_in[0];
  const float* pose     = (const float*)d_in[1];
  const float* mpose_w  = (const float*)d_in[2];
  const float* mpose_b  = (const float*)d_in[3];
  const float* cpose2_w = (const float*)d_in[4];
  const float* cpose2_b = (const float*)d_in[5];
  const float* cw       = (const float*)d_in[6];
  const float* ln_g     = (const float*)d_in[7];
  const float* ln_b     = (const float*)d_in[8];
  const float* sp_w     = (const float*)d_in[9];
  const float* sp_b     = (const float*)d_in[10];

  float* out = (float*)d_out;
  float* ws_h2 = (float*)d_ws;                                  // 16*576 f32
  unsigned short* ws_H  = (unsigned short*)(ws_h2 + 16 * 576);  // 16*82944
  unsigned short* ws_pu = ws_H + 16 * 82944;                    // 784*4608
  unsigned short* ws_cb = ws_pu + 784 * 4608;                   // 784*4608

  hipLaunchKernelGGL(k_htab1, dim3(16, 2), dim3(256), 0, stream, cw, ws_h2);
  hipLaunchKernelGGL(k_htab2, dim3(16, 6), dim3(256), 0, stream, ws_h2, ws_H);
  hipLaunchKernelGGL(k_rowprep, dim3(784), dim3(256), 0, stream,
                     a_img, pose, cpose2_w, cpose2_b, ln_g, ln_b, sp_w, sp_b,
                     out, ws_pu, ws_cb);
  hipLaunchKernelGGL(k_gterm, dim3(896), dim3(512), 0, stream,
                     ws_H, ws_pu, ws_cb, mpose_w, mpose_b, out + 12544);
}

// Round 7
// 180.245 us; speedup vs baseline: 1.8097x; 1.1983x over previous
//
#include <hip/hip_runtime.h>
#include <math.h>

// A=32, B=16, C=16, D=16, KK=9, KKA=288, BSZ=4, L=196, BL=784
// po[b_,d] = sum_t G'_d[t,b_] * x[t,b_,d],  G'_d = (H_d + I) @ coeff
//   H_d[t,n] = h_d[(n-t) mod 288] (row-invariant circulant)
//   x = gelu(pu @ mpose_w_d^T + mb_d) via MFMA, same C/D layout as G'.

typedef __attribute__((ext_vector_type(8))) short bf16x8;
typedef __attribute__((ext_vector_type(4))) float f32x4;

__device__ inline unsigned short f2bf(float f) {
  union { float f; unsigned int i; } v; v.f = f;
  unsigned int r = v.i + 0x7FFFu + ((v.i >> 16) & 1u);
  return (unsigned short)(r >> 16);
}
__device__ inline float gelu_f(float v) {
  return 0.5f * v * (1.f + erff(v * 0.70710678118654752f));
}

// ---------------------------------------------------------------------------
// Kernel 0a: h_d[t] (inverse DFT of the complex filter), doubled, f32.
// ---------------------------------------------------------------------------
__global__ __launch_bounds__(256) void k_htab1(const float* __restrict__ cw,
                                               float* __restrict__ ws_h2) {
  int d = blockIdx.x, tid = threadIdx.x;
  int t = blockIdx.y * 144 + tid;
  if (tid >= 144 || t >= 288) return;
  float acc = cw[(0 * 16 + d) * 2 + 0] +
              ((t & 1) ? -1.f : 1.f) * cw[(144 * 16 + d) * 2 + 0];
  for (int f = 1; f < 144; ++f) {
    int m = (f * t) % 288;
    float th = (float)m * (6.283185307179586f / 288.f);
    float sn, cs;
    sincosf(th, &sn, &cs);
    acc += 2.f * (cw[(f * 16 + d) * 2 + 0] * cs - cw[(f * 16 + d) * 2 + 1] * sn);
  }
  float h = acc * (1.f / 288.f);
  ws_h2[d * 576 + t] = h;
  ws_h2[d * 576 + t + 288] = h;
}

// ---------------------------------------------------------------------------
// Kernel 0b: fragment-ordered (H_d + I) bf16.
// ws_H: [d][mt 18][kk 9][lane 64][j 8]; t = mt*16+(l&15), n = kk*32+(l>>4)*8+j.
// ---------------------------------------------------------------------------
__global__ __launch_bounds__(256) void k_htab2(const float* __restrict__ ws_h2,
                                               unsigned short* __restrict__ ws_H) {
  int d = blockIdx.x, chunk = blockIdx.y, tid = threadIdx.x;
  for (int e = tid; e < 13824; e += 256) {
    int j = e & 7, l = (e >> 3) & 63;
    int kk = (e >> 9) % 9, mtl = (e >> 9) / 9;
    int mt = chunk * 3 + mtl;
    int m = l & 15, g = l >> 4;
    int n = kk * 32 + g * 8 + j, t = mt * 16 + m;
    float v = ws_h2[d * 576 + (n - t + 288)] + ((n == t) ? 1.f : 0.f);
    ws_H[d * 82944 + ((mt * 9 + kk) * 64 + l) * 8 + j] = f2bf(v);
  }
}

// ---------------------------------------------------------------------------
// Kernel 1: per-row prep (round-1 structure), frag-format outputs.
// ---------------------------------------------------------------------------
__global__ __launch_bounds__(256) void k_rowprep(
    const float* __restrict__ a_img, const float* __restrict__ pose,
    const float* __restrict__ cpose2_w, const float* __restrict__ cpose2_b,
    const float* __restrict__ ln_g, const float* __restrict__ ln_b,
    const float* __restrict__ sp_w, const float* __restrict__ sp_b,
    float* __restrict__ out_a, unsigned short* __restrict__ ws_pu,
    unsigned short* __restrict__ ws_cb) {
  __shared__ float s_pu[288 * 17];
  __shared__ float s_lg[288 * 17];
  __shared__ float s_l2[288 * 17];
  __shared__ float s_au[288];
  __shared__ float s_mu[16 * 9], s_rs[16 * 9];
  __shared__ float s_cw[256];
  __shared__ float s_cb[16], s_sw[81], s_sb[9], s_ga[32], s_be[32];
  __shared__ float s_as[16];
  __shared__ float s_aus;

  int tid = threadIdx.x;
  int row = blockIdx.x;
  int b = row / 196, l = row % 196, i0 = l / 14, j0 = l % 14;

  { int r = tid >> 4, c = tid & 15; s_cw[c * 16 + r] = cpose2_w[r * 16 + c]; }
  if (tid < 16) s_cb[tid] = cpose2_b[tid];
  if (tid < 81) s_sw[tid] = sp_w[tid];
  if (tid < 9)  s_sb[tid] = sp_b[tid];
  if (tid < 32) { s_ga[tid] = ln_g[tid]; s_be[tid] = ln_b[tid]; }

  for (int idx = tid; idx < 4608; idx += 256) {
    int n = idx >> 4, c = idx & 15;
    int a = n & 31, kk = n >> 5;
    int ki = kk / 3, kj = kk - 3 * ki;
    int yy = i0 + ki - 1, xx = j0 + kj - 1;
    float v = 0.f;
    if (yy >= 0 && yy < 14 && xx >= 0 && xx < 14)
      v = pose[((b * 512 + a * 16 + c) * 14 + yy) * 14 + xx];
    s_pu[n * 17 + c] = v;
  }
  for (int n = tid; n < 288; n += 256) {
    int a = n & 31, kk = n >> 5;
    int ki = kk / 3, kj = kk - 3 * ki;
    int yy = i0 + ki - 1, xx = j0 + kj - 1;
    float v = 0.f;
    if (yy >= 0 && yy < 14 && xx >= 0 && xx < 14)
      v = a_img[((b * 32 + a) * 14 + yy) * 14 + xx];
    s_au[n] = v;
  }
  __syncthreads();

  for (int idx = tid; idx < 4608; idx += 256) {
    int n = idx >> 4, B = idx & 15;
    float acc = s_cb[B];
#pragma unroll
    for (int c = 0; c < 16; ++c) acc += s_pu[n * 17 + c] * s_cw[c * 16 + B];
    s_lg[n * 17 + B] = acc;
  }
  __syncthreads();

  if (tid < 144) {
    int kk = tid >> 4, B = tid & 15;
    float s = 0.f, s2 = 0.f;
    for (int a = 0; a < 32; ++a) {
      float v = s_lg[(kk * 32 + a) * 17 + B];
      s += v; s2 += v * v;
    }
    float mu = s * (1.f / 32.f);
    float var = s2 * (1.f / 32.f) - mu * mu;
    s_mu[B * 9 + kk] = mu;
    s_rs[B * 9 + kk] = rsqrtf(var + 1e-5f);
  }
  __syncthreads();

  for (int idx = tid; idx < 4608; idx += 256) {
    int n = idx >> 4, B = idx & 15;
    int o = n >> 5, a = n & 31;
    float acc = s_sb[o];
#pragma unroll
    for (int i2 = 0; i2 < 9; ++i2) {
      float v = s_lg[(i2 * 32 + a) * 17 + B];
      float gn = (v - s_mu[B * 9 + i2]) * s_rs[B * 9 + i2] * s_ga[a] + s_be[a];
      acc += s_sw[o * 9 + i2] * gn;
    }
    float ge = 0.5f * acc * (1.f + erff(acc * 0.70710678118654752f));
    s_l2[n * 17 + B] = 2.f * s_lg[n * 17 + B] + ge;
  }
  __syncthreads();

  for (int n = tid; n < 288; n += 256) {
    float m = -1e30f;
#pragma unroll
    for (int B = 0; B < 16; ++B) m = fmaxf(m, s_l2[n * 17 + B]);
    float sum = 0.f;
#pragma unroll
    for (int B = 0; B < 16; ++B) {
      float e = expf(s_l2[n * 17 + B] - m);
      s_l2[n * 17 + B] = e;
      sum += e;
    }
    float inv = 1.f / sum;
#pragma unroll
    for (int B = 0; B < 16; ++B) s_l2[n * 17 + B] *= inv;
  }
  __syncthreads();

  if (tid < 16) {
    float s = 0.f;
    for (int n = 0; n < 288; ++n) s += s_au[n] * s_l2[n * 17 + tid];
    s_as[tid] = s;
  } else if (tid == 16) {
    float s = 0.f;
    for (int n = 0; n < 288; ++n) s += s_au[n];
    s_aus = s;
  }
  __syncthreads();

  if (tid < 16) out_a[(b * 16 + tid) * 196 + l] = s_as[tid] / s_aus;

  // coeff B-frags bf16: e = ((kk*4+g)*16 + b_)*8 + j, n = kk*32+g*8+j
  for (int e = tid; e < 4608; e += 256) {
    int j = e & 7, B = (e >> 3) & 15, g2 = (e >> 7) & 3, kk = e >> 9;
    int n = kk * 32 + g2 * 8 + j;
    float v = s_au[n] * s_l2[n * 17 + B] / s_as[B];
    ws_cb[row * 4608 + e] = f2bf(v);
  }
  // pu compact A-frags: e = (mt*32 + l2)*8 + j, t = mt*16+(l2&15), c=(l2>>4)*8+j
  for (int e = tid; e < 4608; e += 256) {
    int j = e & 7, l2 = (e >> 3) & 31, mt = e >> 8;
    int m = l2 & 15, c = (l2 >> 4) * 8 + j;
    ws_pu[row * 4608 + e] = f2bf(s_pu[(mt * 16 + m) * 17 + c]);
  }
}

// ---------------------------------------------------------------------------
// Kernel 2: barrier-free. grid 1664 = 8 xcd x 13 x 16 d; block = 4 waves,
// all same d, wave = 2 rows (block = 8 rows x d). H frags read directly from
// global (L1-shared within block, L2 XCD-resident). Coeff pinned in VGPRs.
// ---------------------------------------------------------------------------
__global__ __launch_bounds__(256, 3) void k_gterm(
    const unsigned short* __restrict__ ws_H,
    const unsigned short* __restrict__ ws_pu,
    const unsigned short* __restrict__ ws_cb,
    const float* __restrict__ mpose_w, const float* __restrict__ mpose_b,
    float* __restrict__ out_po) {
  int bid = blockIdx.x;
  int xcd = bid & 7, q = bid >> 3;        // q in [0,208)
  int k13 = q % 13, d = q / 13;           // d in [0,16)
  int ro = xcd + 8 * k13;                 // row-octet in [0,104)
  if (ro >= 98) return;

  int tid = threadIdx.x;
  int w = tid >> 6, l = tid & 63;
  int row0 = ro * 8 + w * 2, row1 = row0 + 1;
  int b_ = l & 15, g = l >> 4;

  const bf16x8 z8 = {0, 0, 0, 0, 0, 0, 0, 0};
  const f32x4 zf = {0.f, 0.f, 0.f, 0.f};

  // mpose_w B-frag (k = c, zero-padded c>=16) + bias
  bf16x8 bmw = z8;
  if (g < 2) {
    const float* mp = mpose_w + (b_ * 16 + d) * 16 + g * 8;
#pragma unroll
    for (int j = 0; j < 8; ++j) bmw[j] = (short)f2bf(mp[j]);
  }
  float mb = mpose_b[b_ * 16 + d];

  // coeff B-frags, pinned VGPR-resident
  union CU { uint4 u; bf16x8 v; };
  CU c0[9], c1[9];
  {
    const uint4* gC0 = (const uint4*)ws_cb + row0 * 576;
    const uint4* gC1 = (const uint4*)ws_cb + row1 * 576;
#pragma unroll
    for (int kk = 0; kk < 9; ++kk) {
      c0[kk].u = gC0[kk * 64 + l];
      c1[kk].u = gC1[kk * 64 + l];
    }
#pragma unroll
    for (int kk = 0; kk < 9; ++kk) {
      asm volatile("" : "+v"(c0[kk].u.x), "+v"(c0[kk].u.y),
                        "+v"(c0[kk].u.z), "+v"(c0[kk].u.w));
      asm volatile("" : "+v"(c1[kk].u.x), "+v"(c1[kk].u.y),
                        "+v"(c1[kk].u.z), "+v"(c1[kk].u.w));
    }
  }
  const bf16x8* aP0 = (const bf16x8*)ws_pu + row0 * 576;
  const bf16x8* aP1 = (const bf16x8*)ws_pu + row1 * 576;
  const bf16x8* aH = (const bf16x8*)ws_H + d * 10368;   // 18*9*64 frags

  // prefetch ap for mt=0
  bf16x8 an0 = z8, an1 = z8;
  if (g < 2) { an0 = aP0[l]; an1 = aP1[l]; }

  float po0 = 0.f, po1 = 0.f;
  for (int mt = 0; mt < 18; ++mt) {
    // batched independent H-frag loads (9 x 16B per lane)
    bf16x8 h[9];
#pragma unroll
    for (int kk = 0; kk < 9; ++kk) h[kk] = aH[(mt * 9 + kk) * 64 + l];
    bf16x8 a0 = an0, a1 = an1;
    if (mt < 17 && g < 2) {
      an0 = aP0[(mt + 1) * 32 + l];
      an1 = aP1[(mt + 1) * 32 + l];
    }
    f32x4 xp0 = __builtin_amdgcn_mfma_f32_16x16x32_bf16(a0, bmw, zf, 0, 0, 0);
    f32x4 xp1 = __builtin_amdgcn_mfma_f32_16x16x32_bf16(a1, bmw, zf, 0, 0, 0);
    f32x4 g0 = zf, g1 = zf;
#pragma unroll
    for (int kk = 0; kk < 9; ++kk) {
      g0 = __builtin_amdgcn_mfma_f32_16x16x32_bf16(h[kk], c0[kk].v, g0, 0, 0, 0);
      g1 = __builtin_amdgcn_mfma_f32_16x16x32_bf16(h[kk], c1[kk].v, g1, 0, 0, 0);
    }
#pragma unroll
    for (int r = 0; r < 4; ++r) {
      float s0 = xp0[r] + mb, s1 = xp1[r] + mb;
      po0 += g0[r] * gelu_f(s0);
      po1 += g1[r] * gelu_f(s1);
    }
  }

  po0 += __shfl_xor(po0, 16);
  po0 += __shfl_xor(po0, 32);
  po1 += __shfl_xor(po1, 16);
  po1 += __shfl_xor(po1, 32);
  if (l < 16) {
    int bb = row0 / 196, lc0 = row0 % 196, lc1 = row1 % 196;
    out_po[((bb * 256) + l * 16 + d) * 196 + lc0] = po0;
    out_po[((bb * 256) + l * 16 + d) * 196 + lc1] = po1;
  }
}

// ---------------------------------------------------------------------------
extern "C" void kernel_launch(void* const* d_in, const int* in_sizes, int n_in,
                              void* d_out, int out_size, void* d_ws, size_t ws_size,
                              hipStream_t stream) {
  const float* a_img    = (const float*)d_in[0];
  const float* pose     = (const float*)d_in[1];
  const float* mpose_w  = (const float*)d_in[2];
  const float* mpose_b  = (const float*)d_in[3];
  const float* cpose2_w = (const float*)d_in[4];
  const float* cpose2_b = (const float*)d_in[5];
  const float* cw       = (const float*)d_in[6];
  const float* ln_g     = (const float*)d_in[7];
  const float* ln_b     = (const float*)d_in[8];
  const float* sp_w     = (const float*)d_in[9];
  const float* sp_b     = (const float*)d_in[10];

  float* out = (float*)d_out;
  float* ws_h2 = (float*)d_ws;                                  // 16*576 f32
  unsigned short* ws_H  = (unsigned short*)(ws_h2 + 16 * 576);  // 16*82944
  unsigned short* ws_pu = ws_H + 16 * 82944;                    // 784*4608
  unsigned short* ws_cb = ws_pu + 784 * 4608;                   // 784*4608

  hipLaunchKernelGGL(k_htab1, dim3(16, 2), dim3(256), 0, stream, cw, ws_h2);
  hipLaunchKernelGGL(k_htab2, dim3(16, 6), dim3(256), 0, stream, ws_h2, ws_H);
  hipLaunchKernelGGL(k_rowprep, dim3(784), dim3(256), 0, stream,
                     a_img, pose, cpose2_w, cpose2_b, ln_g, ln_b, sp_w, sp_b,
                     out, ws_pu, ws_cb);
  hipLaunchKernelGGL(k_gterm, dim3(1664), dim3(256), 0, stream,
                     ws_H, ws_pu, ws_cb, mpose_w, mpose_b, out + 12544);
}

// Round 8
// 163.753 us; speedup vs baseline: 1.9920x; 1.1007x over previous
//
#include <hip/hip_runtime.h>
#include <math.h>

// A=32, B=16, C=16, D=16, KK=9, KKA=288, BSZ=4, L=196, BL=784
// po[b_,d] = sum_t G'_d[t,b_] * x[t,b_,d],  G'_d = (H_d + I) @ coeff
//   H_d[t,n] = h_d[(n-t) mod 288] (row-invariant circulant)
//   x = gelu(pu @ mpose_w_d^T + mb_d) via MFMA, same C/D layout as G'.

typedef __attribute__((ext_vector_type(8))) short bf16x8;
typedef __attribute__((ext_vector_type(4))) float f32x4;

__device__ inline float4 ld4(const float* p) { return *reinterpret_cast<const float4*>(p); }
__device__ inline void st4(float* p, float4 v) { *reinterpret_cast<float4*>(p) = v; }
__device__ inline unsigned short f2bf(float f) {
  union { float f; unsigned int i; } v; v.f = f;
  unsigned int r = v.i + 0x7FFFu + ((v.i >> 16) & 1u);
  return (unsigned short)(r >> 16);
}
__device__ inline float gelu_f(float v) {
  return 0.5f * v * (1.f + erff(v * 0.70710678118654752f));
}

// ---------------------------------------------------------------------------
// Kernel 0a: h_d[t] (inverse DFT of the complex filter), doubled, f32.
// ---------------------------------------------------------------------------
__global__ __launch_bounds__(256) void k_htab1(const float* __restrict__ cw,
                                               float* __restrict__ ws_h2) {
  int d = blockIdx.x, tid = threadIdx.x;
  int t = blockIdx.y * 144 + tid;
  if (tid >= 144 || t >= 288) return;
  float acc = cw[(0 * 16 + d) * 2 + 0] +
              ((t & 1) ? -1.f : 1.f) * cw[(144 * 16 + d) * 2 + 0];
  for (int f = 1; f < 144; ++f) {
    int m = (f * t) % 288;
    float th = (float)m * (6.283185307179586f / 288.f);
    float sn, cs;
    sincosf(th, &sn, &cs);
    acc += 2.f * (cw[(f * 16 + d) * 2 + 0] * cs - cw[(f * 16 + d) * 2 + 1] * sn);
  }
  float h = acc * (1.f / 288.f);
  ws_h2[d * 576 + t] = h;
  ws_h2[d * 576 + t + 288] = h;
}

// ---------------------------------------------------------------------------
// Kernel 0b: fragment-ordered (H_d + I) bf16.
// ws_H: [d][mt 18][kk 9][lane 64][j 8]; t = mt*16+(l&15), n = kk*32+(l>>4)*8+j.
// ---------------------------------------------------------------------------
__global__ __launch_bounds__(256) void k_htab2(const float* __restrict__ ws_h2,
                                               unsigned short* __restrict__ ws_H) {
  int d = blockIdx.x, chunk = blockIdx.y, tid = threadIdx.x;
  for (int e = tid; e < 13824; e += 256) {
    int j = e & 7, l = (e >> 3) & 63;
    int kk = (e >> 9) % 9, mtl = (e >> 9) / 9;
    int mt = chunk * 3 + mtl;
    int m = l & 15, g = l >> 4;
    int n = kk * 32 + g * 8 + j, t = mt * 16 + m;
    float v = ws_h2[d * 576 + (n - t + 288)] + ((n == t) ? 1.f : 0.f);
    ws_H[d * 82944 + ((mt * 9 + kk) * 64 + l) * 8 + j] = f2bf(v);
  }
}

// ---------------------------------------------------------------------------
// Kernel 1: per-row prep v3 — register-cached weights, b128 LDS, one-read gate.
// ---------------------------------------------------------------------------
__global__ __launch_bounds__(256) void k_rowprep(
    const float* __restrict__ a_img, const float* __restrict__ pose,
    const float* __restrict__ cpose2_w, const float* __restrict__ cpose2_b,
    const float* __restrict__ ln_g, const float* __restrict__ ln_b,
    const float* __restrict__ sp_w, const float* __restrict__ sp_b,
    float* __restrict__ out_a, unsigned short* __restrict__ ws_pu,
    unsigned short* __restrict__ ws_cb) {
  __shared__ __align__(16) float s_pu[288 * 20];
  __shared__ __align__(16) float s_lg[288 * 20];
  __shared__ __align__(16) float s_l2[288 * 20];
  __shared__ float s_au[288];
  __shared__ float s_mu[144], s_rs[144];   // [kk*16+B]
  __shared__ float s_ga[32], s_be[32];
  __shared__ float s_part[256], s_pau[16];
  __shared__ float s_as[16];

  int tid = threadIdx.x;
  int row = blockIdx.x;
  int b = row / 196, loc = row % 196, i0 = loc / 14, j0 = loc % 14;
  int b_ = tid & 15;

  if (tid < 32) { s_ga[tid] = ln_g[tid]; s_be[tid] = ln_b[tid]; }

  // per-thread register weights (column b_)
  float wcol[16];
#pragma unroll
  for (int q = 0; q < 4; ++q) {
    float4 v = ld4(&cpose2_w[b_ * 16 + 4 * q]);
    wcol[4 * q] = v.x; wcol[4 * q + 1] = v.y;
    wcol[4 * q + 2] = v.z; wcol[4 * q + 3] = v.w;
  }
  float cbv = cpose2_b[b_];

  // unfold pose -> s_pu; a -> s_au
  for (int idx = tid; idx < 4608; idx += 256) {
    int n = idx >> 4, c = idx & 15;
    int a = n & 31, kk = n >> 5;
    int ki = kk / 3, kj = kk - 3 * ki;
    int yy = i0 + ki - 1, xx = j0 + kj - 1;
    float v = 0.f;
    if (yy >= 0 && yy < 14 && xx >= 0 && xx < 14)
      v = pose[((b * 512 + a * 16 + c) * 14 + yy) * 14 + xx];
    s_pu[n * 20 + c] = v;
  }
  for (int n = tid; n < 288; n += 256) {
    int a = n & 31, kk = n >> 5;
    int ki = kk / 3, kj = kk - 3 * ki;
    int yy = i0 + ki - 1, xx = j0 + kj - 1;
    float v = 0.f;
    if (yy >= 0 && yy < 14 && xx >= 0 && xx < 14)
      v = a_img[((b * 32 + a) * 14 + yy) * 14 + xx];
    s_au[n] = v;
  }
  __syncthreads();

  // logit[n,b_]: 18 iters, 4 x b128 reads each
  {
    int n0 = tid >> 4;
#pragma unroll 3
    for (int k = 0; k < 18; ++k) {
      int n = n0 + 16 * k;
      const float* pr = &s_pu[n * 20];
      float acc = cbv;
#pragma unroll
      for (int q = 0; q < 4; ++q) {
        float4 p = ld4(pr + 4 * q);
        acc += p.x * wcol[4 * q] + p.y * wcol[4 * q + 1] +
               p.z * wcol[4 * q + 2] + p.w * wcol[4 * q + 3];
      }
      s_lg[n * 20 + b_] = acc;
    }
  }
  __syncthreads();

  // LN stats (tid<144); aus partials (tid in [144,160))
  if (tid < 144) {
    int kk = tid >> 4, B = tid & 15;
    float s = 0.f, s2 = 0.f;
    for (int a = 0; a < 32; ++a) {
      float v = s_lg[(kk * 32 + a) * 20 + B];
      s += v; s2 += v * v;
    }
    float mu = s * (1.f / 32.f);
    float var = s2 * (1.f / 32.f) - mu * mu;
    s_mu[tid] = mu;
    s_rs[tid] = rsqrtf(var + 1e-5f);
  } else if (tid < 160) {
    int t2 = tid - 144;
    float p = 0.f;
    for (int i = 0; i < 18; ++i) p += s_au[t2 * 18 + i];
    s_pau[t2] = p;
  }
  __syncthreads();

  // gate: thread (a2=tid>>4, b_) handles a in {a2, a2+16}; reads 9 logits once
  {
    float mu9[9], rs9[9];
#pragma unroll
    for (int i2 = 0; i2 < 9; ++i2) {
      mu9[i2] = s_mu[i2 * 16 + b_];
      rs9[i2] = s_rs[i2 * 16 + b_];
    }
#pragma unroll
    for (int half = 0; half < 2; ++half) {
      int a = (tid >> 4) + 16 * half;
      float ga = s_ga[a], be = s_be[a];
      float gn[9], lg9[9];
#pragma unroll
      for (int i2 = 0; i2 < 9; ++i2) {
        float v = s_lg[(i2 * 32 + a) * 20 + b_];
        lg9[i2] = v;
        gn[i2] = (v - mu9[i2]) * rs9[i2] * ga + be;
      }
#pragma unroll
      for (int o = 0; o < 9; ++o) {
        float acc = sp_b[o];                 // uniform -> scalar load
#pragma unroll
        for (int i2 = 0; i2 < 9; ++i2) acc += sp_w[o * 9 + i2] * gn[i2];
        s_l2[(o * 32 + a) * 20 + b_] = 2.f * lg9[o] + gelu_f(acc);
      }
    }
  }
  __syncthreads();

  // softmax over B per n (b128 in/out)
  for (int n = tid; n < 288; n += 256) {
    float v[16];
#pragma unroll
    for (int q = 0; q < 4; ++q) {
      float4 t = ld4(&s_l2[n * 20 + 4 * q]);
      v[4 * q] = t.x; v[4 * q + 1] = t.y; v[4 * q + 2] = t.z; v[4 * q + 3] = t.w;
    }
    float m = v[0];
#pragma unroll
    for (int e = 1; e < 16; ++e) m = fmaxf(m, v[e]);
    float s = 0.f;
#pragma unroll
    for (int e = 0; e < 16; ++e) { v[e] = expf(v[e] - m); s += v[e]; }
    float inv = 1.f / s;
#pragma unroll
    for (int q = 0; q < 4; ++q)
      st4(&s_l2[n * 20 + 4 * q],
          make_float4(v[4 * q] * inv, v[4 * q + 1] * inv, v[4 * q + 2] * inv,
                      v[4 * q + 3] * inv));
  }
  __syncthreads();

  // ar_sum partials
  {
    int sl = tid >> 4;
    float part = 0.f;
#pragma unroll 3
    for (int i = 0; i < 18; ++i) {
      int n = sl * 18 + i;
      part += s_au[n] * s_l2[n * 20 + b_];
    }
    s_part[tid] = part;
  }
  __syncthreads();

  if (tid < 16) {
    float s = 0.f;
#pragma unroll
    for (int q = 0; q < 16; ++q) s += s_part[tid + 16 * q];
    s_as[tid] = s;
    float aus = 0.f;
#pragma unroll
    for (int q = 0; q < 16; ++q) aus += s_pau[q];
    out_a[(b * 16 + tid) * 196 + loc] = s / aus;
  }
  __syncthreads();

  // coeff B-frags bf16: e = ((kk*4+g)*16 + b_)*8 + j, n = kk*32+g*8+j
  {
    float inv_as = 1.f / s_as[(tid >> 3) & 15];
    for (int e = tid; e < 4608; e += 256) {
      int j = e & 7, B = (e >> 3) & 15, g2 = (e >> 7) & 3, kk = e >> 9;
      int n = kk * 32 + g2 * 8 + j;
      float v = s_au[n] * s_l2[n * 20 + B] * inv_as;
      ws_cb[row * 4608 + e] = f2bf(v);
    }
  }
  // pu compact A-frags: e = (mt*32 + l2)*8 + j, t = mt*16+(l2&15), c=(l2>>4)*8+j
  for (int e = tid; e < 4608; e += 256) {
    int j = e & 7, l2 = (e >> 3) & 31, mt = e >> 8;
    int m = l2 & 15, c = (l2 >> 4) * 8 + j;
    ws_pu[row * 4608 + e] = f2bf(s_pu[(mt * 16 + m) * 20 + c]);
  }
}

// ---------------------------------------------------------------------------
// Kernel 2: barrier-free, H double-buffered in registers (prefetch 1 mt ahead).
// grid 1664 = 8 xcd x 13 x 16 d; block = 4 waves same d; wave = 2 rows.
// ---------------------------------------------------------------------------
#define GSTEP(MT, HC, HN)                                                      \
  {                                                                            \
    if ((MT) + 1 < 18) {                                                       \
      _Pragma("unroll")                                                        \
      for (int kk = 0; kk < 9; ++kk)                                           \
        HN[kk] = aH[(((MT) + 1) * 9 + kk) * 64 + l];                           \
    }                                                                          \
    bf16x8 a0 = an0, a1 = an1;                                                 \
    if ((MT) + 1 < 18 && g < 2) {                                              \
      an0 = aP0[((MT) + 1) * 32 + l];                                          \
      an1 = aP1[((MT) + 1) * 32 + l];                                          \
    }                                                                          \
    f32x4 xp0 = __builtin_amdgcn_mfma_f32_16x16x32_bf16(a0, bmw, zf, 0, 0, 0); \
    f32x4 xp1 = __builtin_amdgcn_mfma_f32_16x16x32_bf16(a1, bmw, zf, 0, 0, 0); \
    f32x4 g0 = zf, g1 = zf;                                                    \
    _Pragma("unroll")                                                          \
    for (int kk = 0; kk < 9; ++kk) {                                           \
      g0 = __builtin_amdgcn_mfma_f32_16x16x32_bf16(HC[kk], c0[kk].v, g0, 0, 0, 0); \
      g1 = __builtin_amdgcn_mfma_f32_16x16x32_bf16(HC[kk], c1[kk].v, g1, 0, 0, 0); \
    }                                                                          \
    _Pragma("unroll")                                                          \
    for (int r = 0; r < 4; ++r) {                                              \
      float s0 = xp0[r] + mb, s1 = xp1[r] + mb;                                \
      po0 += g0[r] * gelu_f(s0);                                               \
      po1 += g1[r] * gelu_f(s1);                                               \
    }                                                                          \
  }

__global__ __launch_bounds__(256, 2) void k_gterm(
    const unsigned short* __restrict__ ws_H,
    const unsigned short* __restrict__ ws_pu,
    const unsigned short* __restrict__ ws_cb,
    const float* __restrict__ mpose_w, const float* __restrict__ mpose_b,
    float* __restrict__ out_po) {
  int bid = blockIdx.x;
  int xcd = bid & 7, q = bid >> 3;        // q in [0,208)
  int k13 = q % 13, d = q / 13;           // d in [0,16)
  int ro = xcd + 8 * k13;                 // row-octet in [0,104)
  if (ro >= 98) return;

  int tid = threadIdx.x;
  int w = tid >> 6, l = tid & 63;
  int row0 = ro * 8 + w * 2, row1 = row0 + 1;
  int b_ = l & 15, g = l >> 4;

  const bf16x8 z8 = {0, 0, 0, 0, 0, 0, 0, 0};
  const f32x4 zf = {0.f, 0.f, 0.f, 0.f};

  bf16x8 bmw = z8;
  if (g < 2) {
    const float* mp = mpose_w + (b_ * 16 + d) * 16 + g * 8;
#pragma unroll
    for (int j = 0; j < 8; ++j) bmw[j] = (short)f2bf(mp[j]);
  }
  float mb = mpose_b[b_ * 16 + d];

  union CU { uint4 u; bf16x8 v; };
  CU c0[9], c1[9];
  {
    const uint4* gC0 = (const uint4*)ws_cb + row0 * 576;
    const uint4* gC1 = (const uint4*)ws_cb + row1 * 576;
#pragma unroll
    for (int kk = 0; kk < 9; ++kk) {
      c0[kk].u = gC0[kk * 64 + l];
      c1[kk].u = gC1[kk * 64 + l];
    }
#pragma unroll
    for (int kk = 0; kk < 9; ++kk) {
      asm volatile("" : "+v"(c0[kk].u.x), "+v"(c0[kk].u.y),
                        "+v"(c0[kk].u.z), "+v"(c0[kk].u.w));
      asm volatile("" : "+v"(c1[kk].u.x), "+v"(c1[kk].u.y),
                        "+v"(c1[kk].u.z), "+v"(c1[kk].u.w));
    }
  }
  const bf16x8* aP0 = (const bf16x8*)ws_pu + row0 * 576;
  const bf16x8* aP1 = (const bf16x8*)ws_pu + row1 * 576;
  const bf16x8* aH = (const bf16x8*)ws_H + d * 10368;   // 18*9*64 frags

  // prologue: H tile 0 + ap tile 0
  bf16x8 hA[9], hB[9];
#pragma unroll
  for (int kk = 0; kk < 9; ++kk) hA[kk] = aH[kk * 64 + l];
  bf16x8 an0 = z8, an1 = z8;
  if (g < 2) { an0 = aP0[l]; an1 = aP1[l]; }

  float po0 = 0.f, po1 = 0.f;
  for (int mt2 = 0; mt2 < 9; ++mt2) {
    int mt = 2 * mt2;
    GSTEP(mt, hA, hB);
    GSTEP(mt + 1, hB, hA);
  }

  po0 += __shfl_xor(po0, 16);
  po0 += __shfl_xor(po0, 32);
  po1 += __shfl_xor(po1, 16);
  po1 += __shfl_xor(po1, 32);
  if (l < 16) {
    int bb = row0 / 196, lc0 = row0 % 196, lc1 = row1 % 196;
    out_po[((bb * 256) + l * 16 + d) * 196 + lc0] = po0;
    out_po[((bb * 256) + l * 16 + d) * 196 + lc1] = po1;
  }
}

// ---------------------------------------------------------------------------
extern "C" void kernel_launch(void* const* d_in, const int* in_sizes, int n_in,
                              void* d_out, int out_size, void* d_ws, size_t ws_size,
                              hipStream_t stream) {
  const float* a_img    = (const float*)d_in[0];
  const float* pose     = (const float*)d_in[1];
  const float* mpose_w  = (const float*)d_in[2];
  const float* mpose_b  = (const float*)d_in[3];
  const float* cpose2_w = (const float*)d_in[4];
  const float* cpose2_b = (const float*)d_in[5];
  const float* cw       = (const float*)d_in[6];
  const float* ln_g     = (const float*)d_in[7];
  const float* ln_b     = (const float*)d_in[8];
  const float* sp_w     = (const float*)d_in[9];
  const float* sp_b     = (const float*)d_in[10];

  float* out = (float*)d_out;
  float* ws_h2 = (float*)d_ws;                                  // 16*576 f32
  unsigned short* ws_H  = (unsigned short*)(ws_h2 + 16 * 576);  // 16*82944
  unsigned short* ws_pu = ws_H + 16 * 82944;                    // 784*4608
  unsigned short* ws_cb = ws_pu + 784 * 4608;                   // 784*4608

  hipLaunchKernelGGL(k_htab1, dim3(16, 2), dim3(256), 0, stream, cw, ws_h2);
  hipLaunchKernelGGL(k_htab2, dim3(16, 6), dim3(256), 0, stream, ws_h2, ws_H);
  hipLaunchKernelGGL(k_rowprep, dim3(784), dim3(256), 0, stream,
                     a_img, pose, cpose2_w, cpose2_b, ln_g, ln_b, sp_w, sp_b,
                     out, ws_pu, ws_cb);
  hipLaunchKernelGGL(k_gterm, dim3(1664), dim3(256), 0, stream,
                     ws_H, ws_pu, ws_cb, mpose_w, mpose_b, out + 12544);
}